// Round 1
// baseline (547.746 us; speedup 1.0000x reference)
//
#include <hip/hip_runtime.h>
#include <math.h>

// ---- problem constants ----
#define L_IN      2560000
#define HOP       512
#define NB        84
#define NF        5000            // (L - HOP)/HOP + 1
#define PAD0      6726            // pad of bin 0 (wl0 = 13453, 13453//2)
#define KAL       13568           // kernel row stride, mult of 256, >= 13453
#define XPLEN     2573452         // L + 2*PAD0
#define XPLEN_AL  2573456         // rounded to mult of 4

// ---- workspace layout (in floats) ----
#define XP_OFF  0
#define KR_OFF  XPLEN_AL
#define KI_OFF  (KR_OFF + NB*KAL)
#define TBL_OFF (KI_OFF + NB*KAL)   // int table region lives here

// table layout (ints)
#define T_WL  0
#define T_PAD 84
#define T_FB  168
#define T_JS  252
#define T_JC  336

__global__ void k_table(int* __restrict__ tbl) {
  int b = threadIdx.x;
  if (b >= NB) return;
  double q    = 1.0 / (pow(2.0, 1.0 / 12.0) - 1.0);
  double freq = 20.0 * pow(2.0, (double)b / 12.0);
  double wld  = 16000.0 * q / freq;
  int wl = (int)wld;                       // int() truncation (value >0)
  if (wl > L_IN / 4) wl = L_IN / 4;        // min(..., L//4)
  int pad = wl >> 1;
  int fb = (int)(freq * (double)wl / 16000.0);
  if (fb > wl / 2) fb = wl / 2;
  int js, jc;
  if (wl < 32) { js = 0; jc = 0; }         // skipped bin -> zero row
  else {
    js = (PAD0 - pad) & ~3;                // align down for float4
    int je = PAD0 - pad + wl;              // exclusive end of support
    jc = ((je - js) + 255) & ~255;         // round to 256 (wave*float4)
    if (js + jc > KAL) jc = KAL - js;      // stay inside the row
  }
  tbl[T_WL + b] = wl; tbl[T_PAD + b] = pad; tbl[T_FB + b] = fb;
  tbl[T_JS + b] = js; tbl[T_JC + b] = jc;
}

__global__ void k_xpad(const float* __restrict__ x, float* __restrict__ xp) {
  int i = blockIdx.x * 256 + threadIdx.x;
  if (i >= XPLEN_AL) return;
  float v = 0.f;
  if (i < XPLEN) {
    int u = i - PAD0;
    if (u < 0) u = -u;                       // reflect (no edge repeat)
    else if (u >= L_IN) u = 2 * L_IN - 2 - u;
    v = x[u];
  }
  xp[i] = v;
}

__global__ void k_kgen(const int* __restrict__ tbl,
                       float* __restrict__ Kr, float* __restrict__ Ki) {
  int b  = blockIdx.y;
  int jj = blockIdx.x * 256 + threadIdx.x;   // 0..KAL-1
  int wl = tbl[T_WL + b], pad = tbl[T_PAD + b], fb = tbl[T_FB + b];
  int n = jj - PAD0 + pad;                   // tap index within window
  float kr = 0.f, ki = 0.f;
  if (wl >= 32 && n >= 0 && n < wl) {
    double inv   = 1.0 / (double)wl;
    double twopi = 6.283185307179586476925286766559;
    // hann (periodic) * conj(e^{-i 2 pi fb n / wl}); angles formed in double
    float wn  = 0.5f - 0.5f * cosf((float)(twopi * (double)n * inv));
    float ang = (float)(twopi * (double)(fb * n) * inv);
    kr =  wn * cosf(ang);
    ki = -wn * sinf(ang);
  }
  Kr[(size_t)b * KAL + jj] = kr;
  Ki[(size_t)b * KAL + jj] = ki;
}

// one wave = one bin x 4 consecutive frames; lanes stride taps (float4)
__global__ __launch_bounds__(256) void k_cqt(const float* __restrict__ xp,
                                             const float* __restrict__ Kr,
                                             const float* __restrict__ Ki,
                                             const int* __restrict__ tbl,
                                             float* __restrict__ out) {
  int b    = blockIdx.y;
  int wave = threadIdx.x >> 6;
  int lane = threadIdx.x & 63;
  int t0   = (blockIdx.x * 4 + wave) * 4;    // first of this wave's 4 frames
  if (t0 >= NF) return;                      // NF % 4 == 0 -> no partial waves
  int js = tbl[T_JS + b], jc = tbl[T_JC + b];
  const float* kr = Kr + (size_t)b * KAL;
  const float* ki = Ki + (size_t)b * KAL;
  const float* x0 = xp + (size_t)t0 * HOP;

  float4 ar[4], ai[4];
#pragma unroll
  for (int f = 0; f < 4; f++) {
    ar[f] = make_float4(0.f, 0.f, 0.f, 0.f);
    ai[f] = make_float4(0.f, 0.f, 0.f, 0.f);
  }
  for (int c = js + lane * 4; c < js + jc; c += 256) {
    float4 vr = *(const float4*)(kr + c);
    float4 vi = *(const float4*)(ki + c);
#pragma unroll
    for (int f = 0; f < 4; f++) {
      float4 xv = *(const float4*)(x0 + f * HOP + c);
      ar[f].x += vr.x * xv.x; ar[f].y += vr.y * xv.y;
      ar[f].z += vr.z * xv.z; ar[f].w += vr.w * xv.w;
      ai[f].x += vi.x * xv.x; ai[f].y += vi.y * xv.y;
      ai[f].z += vi.z * xv.z; ai[f].w += vi.w * xv.w;
    }
  }
#pragma unroll
  for (int f = 0; f < 4; f++) {
    float sr = ar[f].x + ar[f].y + ar[f].z + ar[f].w;
    float si = ai[f].x + ai[f].y + ai[f].z + ai[f].w;
#pragma unroll
    for (int o = 32; o >= 1; o >>= 1) {
      sr += __shfl_xor(sr, o, 64);
      si += __shfl_xor(si, o, 64);
    }
    if (lane == 0) out[(size_t)b * NF + t0 + f] = sqrtf(sr * sr + si * si);
  }
}

extern "C" void kernel_launch(void* const* d_in, const int* in_sizes, int n_in,
                              void* d_out, int out_size, void* d_ws, size_t ws_size,
                              hipStream_t stream) {
  const float* x = (const float*)d_in[0];
  float* W   = (float*)d_ws;
  float* xp  = W + XP_OFF;
  float* Kr  = W + KR_OFF;
  float* Ki  = W + KI_OFF;
  int*   tbl = (int*)(W + TBL_OFF);
  float* out = (float*)d_out;

  hipLaunchKernelGGL(k_table, dim3(1), dim3(128), 0, stream, tbl);
  hipLaunchKernelGGL(k_xpad, dim3((XPLEN_AL + 255) / 256), dim3(256), 0, stream, x, xp);
  hipLaunchKernelGGL(k_kgen, dim3(KAL / 256, NB), dim3(256), 0, stream, tbl, Kr, Ki);
  hipLaunchKernelGGL(k_cqt, dim3((NF + 15) / 16, NB), dim3(256), 0, stream,
                     xp, Kr, Ki, tbl, out);
}

// Round 2
// 85.491 us; speedup vs baseline: 6.4070x; 6.4070x over previous
//
#include <hip/hip_runtime.h>
#include <math.h>

// ---- problem constants ----
#define L_IN   2560000
#define HOP    512
#define NB     84
#define NF     5000
#define PAD0   6726                  // wl0 = 13453, pad = wl0//2
#define XPLEN  2573452               // L + 2*PAD0 (valid reflect-padded region)
#define KTOT   13504                 // 13453 padded to 64
#define NS     211                   // KTOT / 64 k-steps
#define MT     3                     // 192 rows / 64
#define NT     79                    // ceil(5000/64)
#define XBLEN  2601664               // (NT*64-1)*512 + KTOT  (bf16 signal length)
#define EA     (MT*NS*4096)          // A elements (192x13504 tile-blocked)

#define BWIN   91520                 // (63*512 + 13504) * 2 bytes : LDS B window
#define ABUF   8192                  // one A k-step tile: 64 rows x 64 taps x 2B
#define LDS_SZ (BWIN + 3*ABUF)       // 116096 B

// ---- workspace layout (bytes) ----
#define XB_B   0                     // bf16 signal, XBLEN*2 = 5203328
#define AG_B   5203456               // bf16 A, EA*2 = 5185536
#define TBL_B  10389504              // int table

#define T_WL  0
#define T_PAD 84
#define T_FB  168

typedef short bf16x8 __attribute__((ext_vector_type(8)));
typedef float f32x4  __attribute__((ext_vector_type(4)));

__device__ inline unsigned short f2bf(float f) {
  unsigned int u = __float_as_uint(f);
  unsigned int r = (u + 0x7fffu + ((u >> 16) & 1u)) >> 16;
  return (unsigned short)r;
}

__device__ inline void load16(void* l, const void* g) {
  __builtin_amdgcn_global_load_lds((const __attribute__((address_space(1))) void*)g,
                                   (__attribute__((address_space(3))) void*)l, 16, 0, 0);
}

__global__ void k_table(int* __restrict__ tbl) {
  int b = threadIdx.x;
  if (b >= NB) return;
  double q    = 1.0 / (pow(2.0, 1.0 / 12.0) - 1.0);
  double freq = 20.0 * pow(2.0, (double)b / 12.0);
  int wl = (int)(16000.0 * q / freq);
  if (wl > L_IN / 4) wl = L_IN / 4;
  int pad = wl >> 1;
  int fb = (int)(freq * (double)wl / 16000.0);
  if (fb > wl / 2) fb = wl / 2;
  tbl[T_WL + b] = wl; tbl[T_PAD + b] = pad; tbl[T_FB + b] = fb;
}

__global__ void k_xb(const float* __restrict__ x, unsigned short* __restrict__ xb) {
  int i = blockIdx.x * 256 + threadIdx.x;
  if (i >= XBLEN) return;
  float v = 0.f;
  if (i < XPLEN) {
    int u = i - PAD0;
    if (u < 0) u = -u;
    else if (u >= L_IN) u = 2 * L_IN - 2 - u;
    v = x[u];
  }
  xb[i] = f2bf(v);
}

// A generator: tile-blocked [mt][ks][row 64][k 64], XOR-swizzled within tile
__global__ void k_agen(const int* __restrict__ tbl, unsigned short* __restrict__ Ag) {
  int idx = blockIdx.x * 256 + threadIdx.x;
  if (idx >= EA) return;
  int within = idx & 4095;
  int tile   = idx >> 12;          // mt*NS + ks
  int ks  = tile % NS;
  int mt  = tile / NS;
  int row = within >> 6;
  int kk  = within & 63;
  int r = mt * 64 + row;
  unsigned short h = 0;
  if (r < 2 * NB) {
    int b = r >> 1;
    int wl = tbl[T_WL + b], pad = tbl[T_PAD + b], fb = tbl[T_FB + b];
    int t = ks * 64 + kk;
    int n = t - (PAD0 - pad);
    if (n >= 0 && n < wl) {
      double twopi = 6.283185307179586476925286766559;
      float wn  = 0.5f - 0.5f * cosf((float)(twopi * (double)n / (double)wl));
      long long m = ((long long)fb * (long long)n) % (long long)wl;
      float ang = (float)(twopi * (double)m / (double)wl);
      float v = (r & 1) ? (-wn * sinf(ang)) : (wn * cosf(ang));
      h = f2bf(v);
    }
  }
  int slot = (tile << 12) + (row << 6) + (kk ^ ((row & 7) << 3));
  Ag[slot] = h;
}

__global__ __launch_bounds__(256, 1) void k_gemm(const unsigned short* __restrict__ Ag,
                                                 const unsigned short* __restrict__ xb,
                                                 float* __restrict__ out) {
  extern __shared__ char lds[];
  char* Bw = lds;
  char* Ab0 = lds + BWIN;
  const int nt = blockIdx.x, mt = blockIdx.y;
  const int tid = threadIdx.x, lane = tid & 63, wv = tid >> 6;
  const int wm = wv >> 1, wn = wv & 1;

  const char* xsrc  = (const char*)xb + ((size_t)nt << 16);           // nt*64*512*2
  const char* Abase = (const char*)Ag + (((size_t)mt * NS) << 13);

  // ---- stage B window (whole xb slice for 64 frames), pre-swizzled source ----
  for (int ci = wv; ci < 90; ci += 4) {
    int o = ci * 1024 + lane * 16;
    if (o < BWIN) {
      int so = o ^ (((o >> 10) & 7) << 4);
      load16(Bw + ci * 1024, xsrc + so);
    }
  }
  // ---- stage A k-steps 0,1 (linear copy; Ag already swizzled) ----
  {
    const char* as0 = Abase;
    const char* as1 = Abase + ABUF;
#pragma unroll
    for (int c = 0; c < 2; ++c) {
      int ci = c * 4 + wv;
      load16(Ab0 + ci * 1024, as0 + ci * 1024 + lane * 16);
    }
#pragma unroll
    for (int c = 0; c < 2; ++c) {
      int ci = c * 4 + wv;
      load16(Ab0 + ABUF + ci * 1024, as1 + ci * 1024 + lane * 16);
    }
  }

  f32x4 acc[2][2];
#pragma unroll
  for (int i = 0; i < 2; ++i)
#pragma unroll
    for (int j = 0; j < 2; ++j) acc[i][j] = (f32x4){0.f, 0.f, 0.f, 0.f};

  for (int ks = 0; ks < NS; ++ks) {
    int pp = ks % 3;
    if (ks + 2 < NS) {
      const char* as = Abase + ((size_t)(ks + 2) << 13);
      char* ab = Ab0 + ((ks + 2) % 3) * ABUF;
#pragma unroll
      for (int c = 0; c < 2; ++c) {
        int ci = c * 4 + wv;
        load16(ab + ci * 1024, as + ci * 1024 + lane * 16);
      }
      asm volatile("s_waitcnt vmcnt(4)" ::: "memory");
    } else if (ks + 1 < NS) {
      asm volatile("s_waitcnt vmcnt(2)" ::: "memory");
    } else {
      asm volatile("s_waitcnt vmcnt(0)" ::: "memory");
    }
    __builtin_amdgcn_s_barrier();
    asm volatile("" ::: "memory");

    const char* Ac = Ab0 + pp * ABUF;
    bf16x8 af[2][2], bfr[2][2];
#pragma unroll
    for (int im = 0; im < 2; ++im)
#pragma unroll
      for (int kk = 0; kk < 2; ++kk) {
        int row = wm * 32 + im * 16 + (lane & 15);
        int ko  = kk * 64 + ((lane >> 4) << 4);
        af[im][kk] = *(const bf16x8*)(Ac + row * 128 + (ko ^ ((row & 7) << 4)));
      }
#pragma unroll
    for (int in_ = 0; in_ < 2; ++in_)
#pragma unroll
      for (int kk = 0; kk < 2; ++kk) {
        int f = wn * 32 + in_ * 16 + (lane & 15);
        int t = ks * 64 + kk * 32 + ((lane >> 4) << 3);
        int o = f * 1024 + t * 2;
        o ^= ((o >> 10) & 7) << 4;
        bfr[in_][kk] = *(const bf16x8*)(Bw + o);
      }
#pragma unroll
    for (int im = 0; im < 2; ++im)
#pragma unroll
      for (int in_ = 0; in_ < 2; ++in_)
#pragma unroll
        for (int kk = 0; kk < 2; ++kk)
          acc[im][in_] = __builtin_amdgcn_mfma_f32_16x16x32_bf16(
              af[im][kk], bfr[in_][kk], acc[im][in_], 0, 0, 0);

    asm volatile("" ::: "memory");
    __builtin_amdgcn_s_barrier();
  }

  // ---- epilogue: magnitude, in-lane (rows 4q..4q+3 = 2 complete re/im pairs) ----
  int f0 = nt * 64;
#pragma unroll
  for (int im = 0; im < 2; ++im)
#pragma unroll
    for (int in_ = 0; in_ < 2; ++in_) {
      f32x4 v = acc[im][in_];
      int col = f0 + wn * 32 + in_ * 16 + (lane & 15);
      int rb  = mt * 64 + wm * 32 + im * 16 + ((lane >> 4) << 2);
      if (col < NF) {
        int b0 = rb >> 1;
        float m0 = sqrtf(v[0] * v[0] + v[1] * v[1]);
        float m1 = sqrtf(v[2] * v[2] + v[3] * v[3]);
        if (b0 < NB)     out[(size_t)b0 * NF + col] = m0;
        if (b0 + 1 < NB) out[(size_t)(b0 + 1) * NF + col] = m1;
      }
    }
}

extern "C" void kernel_launch(void* const* d_in, const int* in_sizes, int n_in,
                              void* d_out, int out_size, void* d_ws, size_t ws_size,
                              hipStream_t stream) {
  const float* x = (const float*)d_in[0];
  char* ws = (char*)d_ws;
  unsigned short* xb = (unsigned short*)(ws + XB_B);
  unsigned short* Ag = (unsigned short*)(ws + AG_B);
  int* tbl           = (int*)(ws + TBL_B);
  float* out = (float*)d_out;

  hipFuncSetAttribute((const void*)k_gemm,
                      hipFuncAttributeMaxDynamicSharedMemorySize, LDS_SZ);

  hipLaunchKernelGGL(k_table, dim3(1), dim3(128), 0, stream, tbl);
  hipLaunchKernelGGL(k_xb, dim3((XBLEN + 255) / 256), dim3(256), 0, stream, x, xb);
  hipLaunchKernelGGL(k_agen, dim3(EA / 256), dim3(256), 0, stream, tbl, Ag);
  hipLaunchKernelGGL(k_gemm, dim3(NT, MT), dim3(256), LDS_SZ, stream, Ag, xb, out);
}

// Round 3
// 60.498 us; speedup vs baseline: 9.0540x; 1.4131x over previous
//
#include <hip/hip_runtime.h>
#include <math.h>

// ---- problem constants ----
#define L_IN   2560000
#define HOP    512
#define NB     84
#define NF     5000
#define PAD0   6726                  // wl0 = 13453, pad = wl0//2
#define XPLEN  2573452               // L + 2*PAD0
#define NS     211                   // K-steps of 64 (13504 taps)
#define MT     3
#define NT     79
#define NBLK   (MT*NT)               // 237
#define XBLEN  2601664               // (NT*64-1)*512 + 13504
#define EA     (MT*NS*4096)          // A elements, tile-blocked

#define XB_NB  10163                 // ceil(XBLEN/256)
#define AG_NB  (EA/256)              // 10128

#define BWIN    91520                // B window bytes: (63*512+13504)*2
#define ABASE_L 91520                // A buffers start in LDS
#define LDS_SZ  (BWIN + 4*2*8192)    // 157056 B

// ---- workspace layout (bytes) ----
#define XB_B 0
#define AG_B 5203456                 // XBLEN*2 rounded up

typedef short bf16x4 __attribute__((ext_vector_type(4)));
typedef short bf16x8 __attribute__((ext_vector_type(8)));
typedef float f32x16 __attribute__((ext_vector_type(16)));

__device__ inline unsigned short f2bf(float f) {
  unsigned int u = __float_as_uint(f);
  return (unsigned short)((u + 0x7fffu + ((u >> 16) & 1u)) >> 16);
}

__device__ inline void load16(void* l, const void* g) {
  __builtin_amdgcn_global_load_lds((const __attribute__((address_space(1))) void*)g,
                                   (__attribute__((address_space(3))) void*)l, 16, 0, 0);
}

// fused: xb (reflect-pad + bf16 cast) and Ag (kernel gen, tile-blocked+swizzled)
__global__ __launch_bounds__(256) void k_prep(const float* __restrict__ x,
                                              unsigned short* __restrict__ xb,
                                              unsigned short* __restrict__ Ag) {
  if (blockIdx.x < XB_NB) {
    int i = blockIdx.x * 256 + threadIdx.x;
    if (i >= XBLEN) return;
    float v = 0.f;
    if (i < XPLEN) {
      int u = i - PAD0;
      if (u < 0) u = -u;
      else if (u >= L_IN) u = 2 * L_IN - 2 - u;
      v = x[u];
    }
    xb[i] = f2bf(v);
  } else {
    int idx = (blockIdx.x - XB_NB) * 256 + threadIdx.x;
    __shared__ int s_wl[4], s_pad[4], s_fb[4];
    int within = idx & 4095;
    int tile   = idx >> 12;            // mt*NS + ks
    int ks  = tile % NS;
    int mtb = tile / NS;
    int row = within >> 6;
    int kk  = within & 63;
    int r = mtb * 64 + row;
    int row0 = (((blockIdx.x - XB_NB) * 256) & 4095) >> 6;   // block spans 4 rows
    if (threadIdx.x < 4) {
      int rr = mtb * 64 + row0 + threadIdx.x;
      int wl = 0, pad = 0, fb = 0;
      if (rr < 2 * NB) {
        int b = rr >> 1;
        double q    = 1.0 / (pow(2.0, 1.0 / 12.0) - 1.0);
        double freq = 20.0 * pow(2.0, (double)b / 12.0);
        wl = (int)(16000.0 * q / freq);
        if (wl > L_IN / 4) wl = L_IN / 4;
        pad = wl >> 1;
        fb = (int)(freq * (double)wl / 16000.0);
        if (fb > wl / 2) fb = wl / 2;
      }
      s_wl[threadIdx.x] = wl; s_pad[threadIdx.x] = pad; s_fb[threadIdx.x] = fb;
    }
    __syncthreads();
    int li = row - row0;
    int wl = s_wl[li], pad = s_pad[li], fb = s_fb[li];
    unsigned short h = 0;
    if (r < 2 * NB && wl >= 32) {
      int t = ks * 64 + kk;
      int n = t - (PAD0 - pad);
      if (n >= 0 && n < wl) {
        double twopi = 6.283185307179586476925286766559;
        float wn  = 0.5f - 0.5f * cosf((float)(twopi * (double)n / (double)wl));
        long long m = ((long long)fb * (long long)n) % (long long)wl;
        float ang = (float)(twopi * (double)m / (double)wl);
        float v = (r & 1) ? (-wn * sinf(ang)) : (wn * cosf(ang));
        h = f2bf(v);
      }
    }
    // store swizzle: element k ^ ((row&7)<<3)  == byte (k*2) ^ ((row&7)<<4)
    int slot = (tile << 12) + (row << 6) + (kk ^ ((row & 7) << 3));
    Ag[slot] = h;
  }
}

// block: 64 rows x 64 frames, K=13504. 4 waves K-split, no main-loop barriers.
__global__ __launch_bounds__(256, 1) void k_gemm(const unsigned short* __restrict__ Ag,
                                                 const unsigned short* __restrict__ xb,
                                                 float* __restrict__ out) {
  extern __shared__ char lds[];
  char* Bw = lds;
  const int tid = threadIdx.x, lane = tid & 63, wv = tid >> 6;

  // chunked bijective XCD map (m204): same-mt blocks cluster per XCD
  int bid = blockIdx.x;
  int xcd = bid & 7, pos = bid >> 3;
  const int q = NBLK / 8, rch = NBLK % 8;       // 29, 5
  int lid = (xcd < rch) ? xcd * (q + 1) + pos : rch * (q + 1) + (xcd - rch) * q + pos;
  int mt = lid / NT, nt = lid - mt * NT;

  const char* xsrc = (const char*)xb + ((size_t)nt << 16);   // nt*64*512*2

  // ---- stage B window via regs, 8B-granular 4-bit XOR swizzle ----
  for (int u = tid; u < BWIN / 16; u += 256) {
    int o = u << 4;
    uint4 v = *(const uint4*)(xsrc + o);
    int sw = ((o >> 10) & 15) << 3;
    *(uint2*)(Bw + (o ^ sw))       = make_uint2(v.x, v.y);
    *(uint2*)(Bw + ((o + 8) ^ sw)) = make_uint2(v.z, v.w);
  }

  // ---- wave-private K ranges + double-buffered A tiles ----
  int base = wv * 53;
  int nks  = (wv < 3) ? 53 : 52;
  const char* Abase = (const char*)Ag + (((size_t)(mt * NS)) << 13);
  char* Ab = lds + ABASE_L + wv * 16384;

#pragma unroll
  for (int pf = 0; pf < 2; ++pf) {
    const char* src = Abase + ((size_t)(base + pf) << 13);
    char* dst = Ab + pf * 8192;
#pragma unroll
    for (int c = 0; c < 8; ++c)
      load16(dst + c * 1024, src + c * 1024 + lane * 16);
  }
  __syncthreads();   // B window + prologue DMA all resident

  f32x16 acc[2][2];
#pragma unroll
  for (int i = 0; i < 2; ++i)
#pragma unroll
    for (int j = 0; j < 2; ++j)
#pragma unroll
      for (int e = 0; e < 16; ++e) acc[i][j][e] = 0.f;

  for (int i = 0; i < nks; ++i) {
    if (i == nks - 1) asm volatile("s_waitcnt vmcnt(0)" ::: "memory");
    else              asm volatile("s_waitcnt vmcnt(8)" ::: "memory");

    const char* Ac = Ab + (i & 1) * 8192;
    bf16x8 af[2][4];
    int ark = (lane >> 5) << 4;                       // k-group byte offset
#pragma unroll
    for (int im = 0; im < 2; ++im) {
      int row = im * 32 + (lane & 31);
      const char* Ar = Ac + row * 128;
      int swz = (row & 7) << 4;
#pragma unroll
      for (int kk = 0; kk < 4; ++kk)
        af[im][kk] = *(const bf16x8*)(Ar + ((kk * 32 + ark) ^ swz));
    }
    bf16x8 bf_[2][4];
    int tbase = (base + i) * 128 + ark;               // t*2 bytes
#pragma unroll
    for (int in_ = 0; in_ < 2; ++in_) {
      int f = in_ * 32 + (lane & 31);
      int ob = f * 1024 + tbase;
#pragma unroll
      for (int kk = 0; kk < 4; ++kk) {
        int o = ob + kk * 32;
        int sw = ((o >> 10) & 15) << 3;
        int lo_a = o ^ sw;
        bf16x4 lo = *(const bf16x4*)(Bw + lo_a);
        bf16x4 hi = *(const bf16x4*)(Bw + (lo_a ^ 8));
        bf_[in_][kk] = __builtin_shufflevector(lo, hi, 0, 1, 2, 3, 4, 5, 6, 7);
      }
    }
    asm volatile("s_waitcnt lgkmcnt(0)" ::: "memory");   // frag reads retired
    __builtin_amdgcn_sched_barrier(0);
    if (i + 2 < nks) {                                   // overwrite current buf
      const char* src = Abase + ((size_t)(base + i + 2) << 13);
      char* dst = Ab + (i & 1) * 8192;
#pragma unroll
      for (int c = 0; c < 8; ++c)
        load16(dst + c * 1024, src + c * 1024 + lane * 16);
    }
#pragma unroll
    for (int im = 0; im < 2; ++im)
#pragma unroll
      for (int in_ = 0; in_ < 2; ++in_)
#pragma unroll
        for (int kk = 0; kk < 4; ++kk)
          acc[im][in_] = __builtin_amdgcn_mfma_f32_32x32x16_bf16(
              af[im][kk], bf_[in_][kk], acc[im][in_], 0, 0, 0);
  }

  // ---- epilogue: cross-wave reduce + magnitude ----
  __syncthreads();
  float* Cw = (float*)(lds + wv * 16384);
#pragma unroll
  for (int im = 0; im < 2; ++im)
#pragma unroll
    for (int in_ = 0; in_ < 2; ++in_) {
      f32x16 v = acc[im][in_];
      int col = in_ * 32 + (lane & 31);
      int rbase = im * 32 + ((lane >> 5) << 2);
#pragma unroll
      for (int reg = 0; reg < 16; ++reg) {
        int rowl = rbase + (reg & 3) + 8 * (reg >> 2);
        Cw[rowl * 64 + col] = v[reg];
      }
    }
  __syncthreads();
#pragma unroll
  for (int rr = 0; rr < 8; ++rr) {
    int r0 = wv * 16 + rr * 2;
    float re = 0.f, imv = 0.f;
#pragma unroll
    for (int t = 0; t < 4; ++t) {
      const float* Ct = (const float*)(lds + t * 16384);
      re  += Ct[r0 * 64 + lane];
      imv += Ct[(r0 + 1) * 64 + lane];
    }
    int gr  = mt * 64 + r0;
    int b   = gr >> 1;
    int col = nt * 64 + lane;
    if (b < NB && col < NF)
      out[(size_t)b * NF + col] = sqrtf(re * re + imv * imv);
  }
}

extern "C" void kernel_launch(void* const* d_in, const int* in_sizes, int n_in,
                              void* d_out, int out_size, void* d_ws, size_t ws_size,
                              hipStream_t stream) {
  const float* x = (const float*)d_in[0];
  char* ws = (char*)d_ws;
  unsigned short* xb = (unsigned short*)(ws + XB_B);
  unsigned short* Ag = (unsigned short*)(ws + AG_B);
  float* out = (float*)d_out;

  hipFuncSetAttribute((const void*)k_gemm,
                      hipFuncAttributeMaxDynamicSharedMemorySize, LDS_SZ);

  hipLaunchKernelGGL(k_prep, dim3(XB_NB + AG_NB), dim3(256), 0, stream, x, xb, Ag);
  hipLaunchKernelGGL(k_gemm, dim3(NBLK), dim3(256), LDS_SZ, stream, Ag, xb, out);
}